// Round 6
// baseline (455.064 us; speedup 1.0000x reference)
//
#include <hip/hip_runtime.h>
#include <hip/hip_bf16.h>

#define N_PTS 12288
#define DIM   64
#define KSEL  16
#define HALF  1536       // phase-1 subset half (subset = 3072)
#define CAP1  8          // phase-1 per-lane LDS buffer depth
#define CAPR  256        // per-row survivor capacity (mean ~72, P(>256)~e^-23)
#define NEG_INF -1e30f

typedef __bf16 bf16x8 __attribute__((ext_vector_type(8)));
typedef float  f32x4  __attribute__((ext_vector_type(4)));

// Shared MFMA chain: acc = -d2/2 (ext carries the norm terms). MUST be the
// identical sequence in phase 1 and phase 2 so accs match bit-exactly.
__device__ __forceinline__ f32x4 acc_tile(bf16x8 ax, bf16x8 a0, bf16x8 a1,
                                          bf16x8 bx, bf16x8 b0, bf16x8 b1)
{
    f32x4 acc = {0.f, 0.f, 0.f, 0.f};
    acc = __builtin_amdgcn_mfma_f32_16x16x32_bf16(ax, bx, acc, 0, 0, 0);
    acc = __builtin_amdgcn_mfma_f32_16x16x32_bf16(a0, b0, acc, 0, 0, 0);
    acc = __builtin_amdgcn_mfma_f32_16x16x32_bf16(a1, b1, acc, 0, 0, 0);
    return acc;
}

// ---------------------------------------------------------------------------
// Kernel A: sigma2 stats (s1, sx), fp64 row norms, bf16 coords copy, and the
// norm-augmentation MFMA rows (ea8 = [h,l,1,1,0..], eb8 = [-.5,-.5,-.5h,-.5l]).
// ---------------------------------------------------------------------------
__global__ __launch_bounds__(256) void stats_kernel(
    const float* __restrict__ coords,
    float* __restrict__ s1, float* __restrict__ sx,
    double* __restrict__ sq64,
    __bf16* __restrict__ chi,
    __bf16* __restrict__ ea8, __bf16* __restrict__ eb8)
{
    __shared__ float colsh[4][64];
    const int lane = threadIdx.x & 63;
    const int wave = threadIdx.x >> 6;
    const int gw   = blockIdx.x * 4 + wave;     // 0..1023
    float colsum = 0.f, sqsum = 0.f;
    for (int r = gw; r < N_PTS; r += 1024) {
        const float x = coords[r * DIM + lane];
        chi[r * DIM + lane] = (__bf16)x;
        colsum += x;
        float  p   = x * x;
        double p64 = (double)x * (double)x;
        #pragma unroll
        for (int off = 32; off > 0; off >>= 1) {
            p   += __shfl_xor(p, off, 64);
            p64 += __shfl_xor(p64, off, 64);
        }
        if (lane == 0) {
            sqsum += p; sq64[r] = p64;
            const __bf16 h  = (__bf16)p;
            const float  hf = (float)h;
            const __bf16 lo = (__bf16)(p - hf);
            bf16x8 ea, eb;
            #pragma unroll
            for (int t = 0; t < 8; ++t) { ea[t] = (__bf16)0.0f; eb[t] = (__bf16)0.0f; }
            ea[0] = h; ea[1] = lo; ea[2] = (__bf16)1.0f; ea[3] = (__bf16)1.0f;
            eb[0] = (__bf16)-0.5f; eb[1] = (__bf16)-0.5f;
            eb[2] = (__bf16)(-0.5f * hf); eb[3] = (__bf16)(-0.5f * (float)lo);
            ((bf16x8*)ea8)[r] = ea;
            ((bf16x8*)eb8)[r] = eb;
        }
    }
    colsh[wave][lane] = colsum;
    __syncthreads();
    if (wave == 0) {
        const float c = colsh[0][lane] + colsh[1][lane]
                      + colsh[2][lane] + colsh[3][lane];
        atomicAdd(&sx[lane], c);
    }
    if (lane == 0) atomicAdd(s1, sqsum);
}

// Ascending-sorted top-8-largest list: w[0] = smallest-of-8 = threshold.
// Caller guarantees c > w[0].
__device__ __forceinline__ void insert8max(float (&w)[8], float c)
{
    #pragma unroll
    for (int t = 0; t < 7; ++t) {
        const bool shift = (w[t + 1] < c);
        const bool place = (!shift) && (w[t] < c);
        w[t] = shift ? w[t + 1] : (place ? c : w[t]);
    }
    if (w[7] < c) w[7] = c;
}

__device__ __forceinline__ void drainmax(const float* buf, int cnt,
                                         float (&w)[8], int tid)
{
    #pragma unroll 1
    for (int p = 0; p < CAP1; ++p) {
        if (p < cnt) {
            const float c = buf[p * 256 + tid];
            if (c > w[0]) insert8max(w, c);
        }
    }
}

// ---------------------------------------------------------------------------
// Phase 1: per-row screening over j-subset [half*1536, +1536); per-lane top-8
// largest accs (2 i-tiles/lane), pool 16 streams/row -> row's top-18 accs
// (descending) to ph1[row][half][0..17]. Block = 32 rows / 4 waves.
// ---------------------------------------------------------------------------
__global__ __launch_bounds__(256) void phase1_kernel(
    const __bf16* __restrict__ chi,
    const __bf16* __restrict__ ea8, const __bf16* __restrict__ eb8,
    float* __restrict__ ph1)                 // [N][2][18]
{
    __shared__ __align__(16) float smem[4096];   // bufs (2x8x256) alias pool (32x128)
    const int tid  = threadIdx.x;
    const int lane = tid & 63;
    const int wave = tid >> 6;
    const int col  = lane & 15;
    const int quad = lane >> 4;
    const int ibase = (int)blockIdx.x * 32;
    const int half  = (int)blockIdx.y;
    const int i0 = ibase + col, i1 = ibase + 16 + col;

    const bf16x8* cp  = (const bf16x8*)chi;
    const bf16x8* eap = (const bf16x8*)ea8;
    const bf16x8* ebp = (const bf16x8*)eb8;
    const bf16x8 zero = {};

    const bf16x8 b00 = cp[i0 * 8 + quad], b01 = cp[i0 * 8 + quad + 4];
    const bf16x8 b10 = cp[i1 * 8 + quad], b11 = cp[i1 * 8 + quad + 4];
    const bf16x8 bx0 = (quad == 0) ? ebp[i0] : zero;
    const bf16x8 bx1 = (quad == 0) ? ebp[i1] : zero;

    float w0[8], w1[8];
    #pragma unroll
    for (int t = 0; t < 8; ++t) { w0[t] = NEG_INF; w1[t] = NEG_INF; }

    float* bf0 = smem;
    float* bf1 = smem + CAP1 * 256;
    int c0 = 0, c1 = 0;
    const int jw = half * HALF + wave * (HALF / 4);

    #pragma unroll 1
    for (int s = 0; s < (HALF / 4) / 16; ++s) {          // 24 steps
        const int j0 = jw + s * 16;
        const int arow = j0 + col;
        const bf16x8 a0 = cp[arow * 8 + quad];
        const bf16x8 a1 = cp[arow * 8 + quad + 4];
        const bf16x8 ax = (quad == 0) ? eap[arow] : zero;
        const f32x4 acc0 = acc_tile(ax, a0, a1, bx0, b00, b01);
        const f32x4 acc1 = acc_tile(ax, a0, a1, bx1, b10, b11);
        #pragma unroll
        for (int r = 0; r < 4; ++r) {
            const float ca = acc0[r], cb = acc1[r];
            if (ca > w0[0]) { bf0[c0 * 256 + tid] = ca; ++c0; }
            if (cb > w1[0]) { bf1[c1 * 256 + tid] = cb; ++c1; }
        }
        const int cmax = (c0 > c1) ? c0 : c1;
        if (__any(cmax >= 5)) {
            drainmax(bf0, c0, w0, tid);
            drainmax(bf1, c1, w1, tid);
            c0 = 0; c1 = 0;
        }
    }
    drainmax(bf0, c0, w0, tid);
    drainmax(bf1, c1, w1, tid);

    __syncthreads();                    // bufs dead; alias as pool [32][128]
    float* pool = smem;
    const int slot = wave * 4 + quad;   // 16 streams per row
    #pragma unroll
    for (int t = 0; t < 8; ++t) {
        pool[col * 128 + slot * 8 + t]        = w0[t];
        pool[(16 + col) * 128 + slot * 8 + t] = w1[t];
    }
    __syncthreads();

    // Per row: extract top-18 largest of 16 sorted-asc 8-lists (descending).
    #pragma unroll 1
    for (int rr = 0; rr < 8; ++rr) {
        const int row = wave * 8 + rr;
        float cur = (lane < 16) ? pool[row * 128 + lane * 8 + 7] : NEG_INF;
        int idx = 0;
        #pragma unroll 1
        for (int k = 0; k < 18; ++k) {
            float m = cur; int src = lane;
            #pragma unroll
            for (int off = 1; off < 64; off <<= 1) {
                const float o  = __shfl_xor(m, off, 64);
                const int   os = __shfl_xor(src, off, 64);
                if (o > m || (o == m && os < src)) { m = o; src = os; }
            }
            if (lane == 0) ph1[((ibase + row) * 2 + half) * 18 + k] = m;
            if (src == lane) {
                ++idx;
                cur = (idx < 8) ? pool[row * 128 + lane * 8 + 7 - idx] : NEG_INF;
            }
        }
    }
}

// ---------------------------------------------------------------------------
// Phase 1b: T[row] = 18th largest of the two halves' top-18 lists (exact
// subset-18th). One wave per row; bitonic-64 ascending, take element 46.
// ---------------------------------------------------------------------------
__global__ __launch_bounds__(256) void phase1b_kernel(
    const float* __restrict__ ph1, float* __restrict__ T)
{
    const int lane = threadIdx.x & 63;
    const int wave = threadIdx.x >> 6;
    const int row  = (int)blockIdx.x * 4 + wave;
    float v = (lane < 36) ? ph1[row * 36 + lane] : NEG_INF;
    #pragma unroll
    for (int k = 2; k <= 64; k <<= 1) {
        #pragma unroll
        for (int j = k >> 1; j > 0; j >>= 1) {
            const float o = __shfl_xor(v, j, 64);
            const bool up = ((lane & k) == 0);
            const bool keepmin = (((lane & j) == 0) == up);
            v = keepmin ? fminf(v, o) : fmaxf(v, o);
        }
    }
    const float t18 = __shfl(v, 46, 64);     // 18th largest of 64 (asc idx 46)
    if (lane == 0) T[row] = t18;
}

// ---------------------------------------------------------------------------
// Phase 2: stateless full N^2 screen. Block = 64 rows (4 i-tiles) / 4 waves,
// each wave scans 512 j's of its chunk. accept acc >= T[row] -> register
// stash -> per-row global u16 survivor list via atomic counters. No LDS.
// ---------------------------------------------------------------------------
__global__ __launch_bounds__(256) void phase2_kernel(
    const __bf16* __restrict__ chi,
    const __bf16* __restrict__ ea8, const __bf16* __restrict__ eb8,
    const float* __restrict__ T,
    unsigned* __restrict__ ctr,
    unsigned short* __restrict__ wsknn)      // [N][CAPR]
{
    const int lane = threadIdx.x & 63;
    const int wave = threadIdx.x >> 6;
    const int col  = lane & 15;
    const int quad = lane >> 4;
    const int ibase = (int)blockIdx.x * 64;

    const bf16x8* cp  = (const bf16x8*)chi;
    const bf16x8* eap = (const bf16x8*)ea8;
    const bf16x8* ebp = (const bf16x8*)eb8;
    const bf16x8 zero = {};

    bf16x8 b0[4], b1[4], bx[4]; float Tf[4];
    #pragma unroll
    for (int t = 0; t < 4; ++t) {
        const int irow = ibase + 16 * t + col;
        b0[t] = cp[irow * 8 + quad];
        b1[t] = cp[irow * 8 + quad + 4];
        bx[t] = (quad == 0) ? ebp[irow] : zero;
        Tf[t] = T[irow];
    }

    unsigned stash[8]; int cnt = 0;
    const int jw = (int)blockIdx.y * 2048 + wave * 512;

    #pragma unroll 1
    for (int s = 0; s < 32; ++s) {
        const int j0 = jw + s * 16;
        const int arow = j0 + col;
        const bf16x8 a0 = cp[arow * 8 + quad];
        const bf16x8 a1 = cp[arow * 8 + quad + 4];
        const bf16x8 ax = (quad == 0) ? eap[arow] : zero;
        #pragma unroll
        for (int t = 0; t < 4; ++t) {
            const f32x4 acc = acc_tile(ax, a0, a1, bx[t], b0[t], b1[t]);
            #pragma unroll
            for (int r = 0; r < 4; ++r) {
                if (acc[r] >= Tf[t]) {                       // rare (~0.6%)
                    const unsigned ent = ((unsigned)t << 14)
                                       | (unsigned)(j0 + quad * 4 + r);
                    #pragma unroll
                    for (int q = 0; q < 8; ++q) if (q == cnt) stash[q] = ent;
                    ++cnt;
                    if (cnt == 8) {
                        #pragma unroll
                        for (int q = 0; q < 8; ++q) {
                            const unsigned e = stash[q];
                            const int row = ibase + 16 * (int)(e >> 14) + col;
                            const unsigned pos = atomicAdd(&ctr[row], 1u);
                            if (pos < CAPR)
                                wsknn[row * CAPR + pos] =
                                    (unsigned short)(e & 0x3FFFu);
                        }
                        cnt = 0;
                    }
                }
            }
        }
    }
    #pragma unroll
    for (int q = 0; q < 8; ++q) {
        if (q < cnt) {
            const unsigned e = stash[q];
            const int row = ibase + 16 * (int)(e >> 14) + col;
            const unsigned pos = atomicAdd(&ctr[row], 1u);
            if (pos < CAPR)
                wsknn[row * CAPR + pos] = (unsigned short)(e & 0x3FFFu);
        }
    }
}

// ---------------------------------------------------------------------------
// Merge: wave per row. fp64-refine all survivors (<=256, 4 slots/lane),
// 16x extract-min (tie-break slot order), fp64 exp/laplacian, fp32 out.
// ---------------------------------------------------------------------------
__global__ __launch_bounds__(256) void merge_kernel(
    const float* __restrict__ coords,
    const float* __restrict__ pot,
    const double* __restrict__ sq64,
    const float* __restrict__ s1, const float* __restrict__ sx,
    const unsigned* __restrict__ ctr,
    const unsigned short* __restrict__ wsknn,
    float* __restrict__ out)
{
    __shared__ double sInv;
    const int tid  = threadIdx.x;
    const int lane = tid & 63;
    const int wave = tid >> 6;
    const int row  = (int)blockIdx.x * 4 + wave;

    if (tid == 0) {
        double S1 = (double)s1[0], m2 = 0.0;
        for (int d = 0; d < DIM; ++d) { double t = (double)sx[d]; m2 += t * t; }
        const double NN = (double)N_PTS;
        sInv = 1.0 / ((2.0 * NN * S1 - 2.0 * m2) / (NN * NN)
                      + 1e-5 + 1e6 / NN + 1e-5);
    }

    const int L = min((int)ctr[row], CAPR);
    const float4* xip = (const float4*)(coords + row * DIM);
    float4 xi[16];
    #pragma unroll
    for (int q = 0; q < 16; ++q) xi[q] = xip[q];
    const double sqi = sq64[row];

    double dreg[4]; int jreg[4];
    #pragma unroll 1
    for (int b = 0; b < 4; ++b) {
        const int t = b * 64 + lane;
        const int j = (t < L) ? (int)wsknn[row * CAPR + t] : row;
        const float4* xjp = (const float4*)(coords + j * DIM);
        double dot = 0.0;
        #pragma unroll
        for (int q = 0; q < 16; ++q) {
            const float4 a = xi[q], bb = xjp[q];
            dot += (double)a.x * (double)bb.x + (double)a.y * (double)bb.y
                 + (double)a.z * (double)bb.z + (double)a.w * (double)bb.w;
        }
        double d2 = sqi + sq64[j] + 1e-5 - 2.0 * dot;
        if (j == row || t >= L) d2 = 1e300;
        dreg[b] = d2; jreg[b] = j;
    }
    __syncthreads();
    const double inv = sInv;
    const double vr  = (double)pot[row];

    double lap = 0.0;
    #pragma unroll 1
    for (int k = 0; k < KSEL; ++k) {
        double m = dreg[0]; int slot = lane; int jm = jreg[0];
        #pragma unroll
        for (int b = 1; b < 4; ++b)
            if (dreg[b] < m) { m = dreg[b]; slot = b * 64 + lane; jm = jreg[b]; }
        #pragma unroll
        for (int off = 1; off < 64; off <<= 1) {
            const double od = __shfl_xor(m, off, 64);
            const int    os = __shfl_xor(slot, off, 64);
            const int    oj = __shfl_xor(jm, off, 64);
            if (od < m || (od == m && os < slot)) { m = od; slot = os; jm = oj; }
        }
        const double w = exp(-m * inv);
        lap += w * ((double)pot[jm] - vr);
        if ((slot & 63) == lane) {
            const int b2 = slot >> 6;
            #pragma unroll
            for (int b = 0; b < 4; ++b) if (b == b2) dreg[b] = 1e300;
        }
    }
    if (lane == 0) out[row] = (float)lap;
}

extern "C" void kernel_launch(void* const* d_in, const int* in_sizes, int n_in,
                              void* d_out, int out_size, void* d_ws, size_t ws_size,
                              hipStream_t stream)
{
    (void)in_sizes; (void)n_in; (void)out_size; (void)ws_size;
    const float* coords = (const float*)d_in[0];
    const float* pot    = (const float*)d_in[1];
    // d_in[2] is k (always 16, compiled in as KSEL)

    char* w = (char*)d_ws;
    float*    s1    = (float*)w;                       // 4 B
    float*    sx    = (float*)(w + 16);                // 256 B
    unsigned* ctr   = (unsigned*)(w + 288);            // 49152 B
    double*   sq64  = (double*)(w + 49472);            // 98304 B
    __bf16*   chi   = (__bf16*)(w + 147776);           // 1572864 B
    __bf16*   ea8   = (__bf16*)(w + 1720640);          // 196608 B
    __bf16*   eb8   = (__bf16*)(w + 1917248);          // 196608 B
    float*    Tarr  = (float*)(w + 2113856);           // 49152 B
    unsigned short* wsknn = (unsigned short*)(w + 2163008);  // 6291456 B
    float*    ph1   = (float*)(w + 2163008);           // aliases wsknn (dead after 1b)
    // total = 8,454,464 B <= proven ws (round-5 ran the 9.05 MB branch)

    hipMemsetAsync(w, 0, 49440, stream);               // s1, sx, ctr
    stats_kernel<<<dim3(256), dim3(256), 0, stream>>>(
        coords, s1, sx, sq64, chi, ea8, eb8);
    phase1_kernel<<<dim3(N_PTS / 32, 2), dim3(256), 0, stream>>>(
        chi, ea8, eb8, ph1);
    phase1b_kernel<<<dim3(N_PTS / 4), dim3(256), 0, stream>>>(ph1, Tarr);
    phase2_kernel<<<dim3(N_PTS / 64, 6), dim3(256), 0, stream>>>(
        chi, ea8, eb8, Tarr, ctr, wsknn);
    merge_kernel<<<dim3(N_PTS / 4), dim3(256), 0, stream>>>(
        coords, pot, sq64, s1, sx, ctr, wsknn, (float*)d_out);
}

// Round 7
// 398.721 us; speedup vs baseline: 1.1413x; 1.1413x over previous
//
#include <hip/hip_runtime.h>
#include <hip/hip_bf16.h>

#define N_PTS 12288
#define DIM   64
#define KSEL  16
#define CAPR  256        // per-row survivor capacity

typedef __bf16 bf16x8 __attribute__((ext_vector_type(8)));
typedef float  f32x4  __attribute__((ext_vector_type(4)));

// Shared MFMA chain: acc = -d2_screen/2 (ext rows carry the norm terms).
// Identical sequence in count and emit so accs match bit-exactly.
__device__ __forceinline__ f32x4 acc_tile(bf16x8 ax, bf16x8 a0, bf16x8 a1,
                                          bf16x8 bx, bf16x8 b0, bf16x8 b1)
{
    f32x4 acc = {0.f, 0.f, 0.f, 0.f};
    acc = __builtin_amdgcn_mfma_f32_16x16x32_bf16(ax, bx, acc, 0, 0, 0);
    acc = __builtin_amdgcn_mfma_f32_16x16x32_bf16(a0, b0, acc, 0, 0, 0);
    acc = __builtin_amdgcn_mfma_f32_16x16x32_bf16(a1, b1, acc, 0, 0, 0);
    return acc;
}

// Per-row tier thresholds on the d2 scale (Gaussian moment model; the
// measured-count certificate in tsel makes correctness independent of it).
__device__ __forceinline__ void tier_thresholds(float sqr, float S1, float S2,
                                                float (&T)[4])
{
    const float mu_sq  = S1 * (1.0f / N_PTS);
    const float var_sq = S2 * (1.0f / N_PTS) - mu_sq * mu_sq;   // ~128
    const float mu  = sqr + mu_sq;
    const float sig = sqrtf(fmaxf(var_sq, 0.f) + 4.0f * sqr);
    T[0] = mu - 2.90f * sig;
    T[1] = mu - 2.55f * sig;
    T[2] = mu - 2.20f * sig;
    T[3] = mu - 1.90f * sig;
}

// ---------------------------------------------------------------------------
// Kernel A (stats): S1/S2/Sx moments, fp32+fp64 row norms, bf16 coords copy,
// norm-augmentation MFMA rows ea8=[h,l,1,1,0..], eb8=[-.5,-.5,-.5h,-.5l,0..].
// ---------------------------------------------------------------------------
__global__ __launch_bounds__(256) void stats_kernel(
    const float* __restrict__ coords,
    float* __restrict__ s1, float* __restrict__ s2, float* __restrict__ sx,
    float* __restrict__ sq, double* __restrict__ sq64,
    __bf16* __restrict__ chi,
    __bf16* __restrict__ ea8, __bf16* __restrict__ eb8)
{
    __shared__ float colsh[4][64];
    const int lane = threadIdx.x & 63;
    const int wave = threadIdx.x >> 6;
    const int gw   = blockIdx.x * 4 + wave;     // 0..1023
    float colsum = 0.f, sqsum = 0.f, sq2sum = 0.f;
    for (int r = gw; r < N_PTS; r += 1024) {
        const float x = coords[r * DIM + lane];
        chi[r * DIM + lane] = (__bf16)x;
        colsum += x;
        float  p   = x * x;
        double p64 = (double)x * (double)x;
        #pragma unroll
        for (int off = 32; off > 0; off >>= 1) {
            p   += __shfl_xor(p, off, 64);
            p64 += __shfl_xor(p64, off, 64);
        }
        if (lane == 0) {
            sq[r] = p; sq64[r] = p64;
            sqsum += p; sq2sum += p * p;
            const __bf16 h  = (__bf16)p;
            const float  hf = (float)h;
            const __bf16 lo = (__bf16)(p - hf);
            bf16x8 ea, eb;
            #pragma unroll
            for (int t = 0; t < 8; ++t) { ea[t] = (__bf16)0.0f; eb[t] = (__bf16)0.0f; }
            ea[0] = h; ea[1] = lo; ea[2] = (__bf16)1.0f; ea[3] = (__bf16)1.0f;
            eb[0] = (__bf16)-0.5f; eb[1] = (__bf16)-0.5f;
            eb[2] = (__bf16)(-0.5f * hf); eb[3] = (__bf16)(-0.5f * (float)lo);
            ((bf16x8*)ea8)[r] = ea;
            ((bf16x8*)eb8)[r] = eb;
        }
    }
    colsh[wave][lane] = colsum;
    __syncthreads();
    if (wave == 0) {
        const float c = colsh[0][lane] + colsh[1][lane]
                      + colsh[2][lane] + colsh[3][lane];
        atomicAdd(&sx[lane], c);
    }
    if (lane == 0) { atomicAdd(s1, sqsum); atomicAdd(s2, sq2sum); }
}

// ---------------------------------------------------------------------------
// tcalc: strict count-thresholds on the acc scale: acc >= ts  <=>  d2_s <= T-1
// ---------------------------------------------------------------------------
__global__ __launch_bounds__(256) void tcalc_kernel(
    const float* __restrict__ sq,
    const float* __restrict__ s1, const float* __restrict__ s2,
    float* __restrict__ ts)                  // [4][N]
{
    const int r = (int)blockIdx.x * 256 + threadIdx.x;
    float T[4];
    tier_thresholds(sq[r], s1[0], s2[0], T);
    #pragma unroll
    for (int u = 0; u < 4; ++u)
        ts[u * N_PTS + r] = -(T[u] - 1.0f) * 0.5f;
}

// ---------------------------------------------------------------------------
// Count pass: stateless full N^2 screen, 4 tiers, register counters only.
// Block = 64 rows (4 i-tiles) / 4 waves; wave scans 384 j's of its y-chunk.
// ---------------------------------------------------------------------------
__global__ __launch_bounds__(256) void count_kernel(
    const __bf16* __restrict__ chi,
    const __bf16* __restrict__ ea8, const __bf16* __restrict__ eb8,
    const float* __restrict__ ts,
    unsigned* __restrict__ ctrT)             // [4][N]
{
    const int lane = threadIdx.x & 63;
    const int wave = threadIdx.x >> 6;
    const int col  = lane & 15;
    const int quad = lane >> 4;
    const int ibase = (int)blockIdx.x * 64;

    const bf16x8* cp  = (const bf16x8*)chi;
    const bf16x8* eap = (const bf16x8*)ea8;
    const bf16x8* ebp = (const bf16x8*)eb8;
    const bf16x8 zero = {};

    bf16x8 b0[4], b1[4], bx[4]; int rowv[4]; float th[4][4];
    #pragma unroll
    for (int t = 0; t < 4; ++t) {
        rowv[t] = ibase + 16 * t + col;
        b0[t] = cp[rowv[t] * 8 + quad];
        b1[t] = cp[rowv[t] * 8 + quad + 4];
        bx[t] = (quad == 0) ? ebp[rowv[t]] : zero;
        #pragma unroll
        for (int u = 0; u < 4; ++u) th[t][u] = ts[u * N_PTS + rowv[t]];
    }

    int cnt[4][4];
    #pragma unroll
    for (int t = 0; t < 4; ++t)
        #pragma unroll
        for (int u = 0; u < 4; ++u) cnt[t][u] = 0;

    const int jw = (int)blockIdx.y * 1536 + wave * 384;
    #pragma unroll 1
    for (int s = 0; s < 24; ++s) {
        const int j0 = jw + s * 16;
        const int arow = j0 + col;
        const bf16x8 a0 = cp[arow * 8 + quad];
        const bf16x8 a1 = cp[arow * 8 + quad + 4];
        const bf16x8 ax = (quad == 0) ? eap[arow] : zero;
        #pragma unroll
        for (int t = 0; t < 4; ++t) {
            const f32x4 acc = acc_tile(ax, a0, a1, bx[t], b0[t], b1[t]);
            #pragma unroll
            for (int r = 0; r < 4; ++r) {
                #pragma unroll
                for (int u = 0; u < 4; ++u)
                    cnt[t][u] += (acc[r] >= th[t][u]) ? 1 : 0;
            }
        }
    }
    // quad-reduce (lanes sharing a row differ only in quad bits) -> 1 atomic/4
    #pragma unroll
    for (int t = 0; t < 4; ++t)
        #pragma unroll
        for (int u = 0; u < 4; ++u) {
            int c = cnt[t][u];
            c += __shfl_xor(c, 16, 64);
            c += __shfl_xor(c, 32, 64);
            if (quad == 0) atomicAdd(&ctrT[u * N_PTS + rowv[t]], (unsigned)c);
        }
}

// ---------------------------------------------------------------------------
// tsel: pick tightest tier whose measured strict count certifies (>=17 incl
// self, <=220 for CAPR headroom); emit threshold = -(T+1)/2; else flag.
// ---------------------------------------------------------------------------
__global__ __launch_bounds__(256) void tsel_kernel(
    const float* __restrict__ sq,
    const float* __restrict__ s1, const float* __restrict__ s2,
    const unsigned* __restrict__ ctrT,
    unsigned* __restrict__ flagA, float* __restrict__ tE)
{
    const int r = (int)blockIdx.x * 256 + threadIdx.x;
    float T[4];
    tier_thresholds(sq[r], s1[0], s2[0], T);
    unsigned csel = 0xFFFFFFFFu; float Tsel = 0.f;
    #pragma unroll
    for (int u = 0; u < 4; ++u) {
        const unsigned c = ctrT[u * N_PTS + r];
        if (csel == 0xFFFFFFFFu && c >= 17u) { csel = c; Tsel = T[u]; }
    }
    const bool flag = (csel == 0xFFFFFFFFu) || (csel > 220u);
    flagA[r] = flag ? 1u : 0u;
    tE[r] = flag ? 3.0e38f : -(Tsel + 1.0f) * 0.5f;
}

// ---------------------------------------------------------------------------
// Emit pass: same stateless scan; rare accepted j's appended to per-row u16
// lists via atomic counters.
// ---------------------------------------------------------------------------
__global__ __launch_bounds__(256) void emit_kernel(
    const __bf16* __restrict__ chi,
    const __bf16* __restrict__ ea8, const __bf16* __restrict__ eb8,
    const float* __restrict__ tE,
    unsigned* __restrict__ ctrE,
    unsigned short* __restrict__ wsknn)      // [N][CAPR]
{
    const int lane = threadIdx.x & 63;
    const int wave = threadIdx.x >> 6;
    const int col  = lane & 15;
    const int quad = lane >> 4;
    const int ibase = (int)blockIdx.x * 64;

    const bf16x8* cp  = (const bf16x8*)chi;
    const bf16x8* eap = (const bf16x8*)ea8;
    const bf16x8* ebp = (const bf16x8*)eb8;
    const bf16x8 zero = {};

    bf16x8 b0[4], b1[4], bx[4]; int rowv[4]; float thE[4];
    #pragma unroll
    for (int t = 0; t < 4; ++t) {
        rowv[t] = ibase + 16 * t + col;
        b0[t] = cp[rowv[t] * 8 + quad];
        b1[t] = cp[rowv[t] * 8 + quad + 4];
        bx[t] = (quad == 0) ? ebp[rowv[t]] : zero;
        thE[t] = tE[rowv[t]];
    }

    const int jw = (int)blockIdx.y * 1536 + wave * 384;
    #pragma unroll 1
    for (int s = 0; s < 24; ++s) {
        const int j0 = jw + s * 16;
        const int arow = j0 + col;
        const bf16x8 a0 = cp[arow * 8 + quad];
        const bf16x8 a1 = cp[arow * 8 + quad + 4];
        const bf16x8 ax = (quad == 0) ? eap[arow] : zero;
        #pragma unroll
        for (int t = 0; t < 4; ++t) {
            const f32x4 acc = acc_tile(ax, a0, a1, bx[t], b0[t], b1[t]);
            #pragma unroll
            for (int r = 0; r < 4; ++r) {
                if (acc[r] >= thE[t]) {
                    const unsigned pos = atomicAdd(&ctrE[rowv[t]], 1u);
                    if (pos < CAPR)
                        wsknn[rowv[t] * CAPR + pos] =
                            (unsigned short)(j0 + quad * 4 + r);
                }
            }
        }
    }
}

// ---------------------------------------------------------------------------
// Fallback: flagged/overflowed rows get an exact full rescan (fp32 d2 in LDS,
// 24x extract-min -> survivors). Near-zero cost when nothing is flagged.
// ---------------------------------------------------------------------------
__global__ __launch_bounds__(256) void fallback_kernel(
    const float* __restrict__ coords, const float* __restrict__ sq,
    const unsigned* __restrict__ flagA,
    unsigned* __restrict__ ctrE, unsigned short* __restrict__ wsknn)
{
    __shared__ float d2s[N_PTS];
    __shared__ unsigned char flg[64];
    __shared__ float rv[4]; __shared__ int ri[4];
    const int tid = threadIdx.x;
    const int rbase = (int)blockIdx.x * 64;
    if (tid < 64)
        flg[tid] = (flagA[rbase + tid] || ctrE[rbase + tid] > CAPR) ? 1 : 0;
    __syncthreads();
    #pragma unroll 1
    for (int rr = 0; rr < 64; ++rr) {
        if (!flg[rr]) continue;
        const int row = rbase + rr;
        float4 xi[16];
        const float4* xp = (const float4*)(coords + row * DIM);
        #pragma unroll
        for (int q = 0; q < 16; ++q) xi[q] = xp[q];
        const float sqr = sq[row];
        for (int j = tid; j < N_PTS; j += 256) {
            const float4* yp = (const float4*)(coords + j * DIM);
            float dot = 0.f;
            #pragma unroll
            for (int q = 0; q < 16; ++q) {
                const float4 b = yp[q];
                dot += xi[q].x * b.x + xi[q].y * b.y
                     + xi[q].z * b.z + xi[q].w * b.w;
            }
            d2s[j] = sqr + sq[j] - 2.f * dot;
        }
        __syncthreads();
        if (tid == 0) d2s[row] = 3e38f;
        __syncthreads();
        #pragma unroll 1
        for (int k = 0; k < 24; ++k) {
            float m = 3e38f; int mi = 0;
            for (int j = tid; j < N_PTS; j += 256)
                if (d2s[j] < m) { m = d2s[j]; mi = j; }
            #pragma unroll
            for (int off = 1; off < 64; off <<= 1) {
                const float om = __shfl_xor(m, off, 64);
                const int   oi = __shfl_xor(mi, off, 64);
                if (om < m || (om == m && oi < mi)) { m = om; mi = oi; }
            }
            if ((tid & 63) == 0) { rv[tid >> 6] = m; ri[tid >> 6] = mi; }
            __syncthreads();
            if (tid == 0) {
                float bm = rv[0]; int bi = ri[0];
                for (int u = 1; u < 4; ++u)
                    if (rv[u] < bm || (rv[u] == bm && ri[u] < bi)) {
                        bm = rv[u]; bi = ri[u];
                    }
                wsknn[row * CAPR + k] = (unsigned short)bi;
                d2s[bi] = 3e38f;
            }
            __syncthreads();
        }
        if (tid == 0) ctrE[row] = 24;
        __syncthreads();
    }
}

// ---------------------------------------------------------------------------
// Merge (round-6 proven): wave per row, fp64 refine of <=256 survivors,
// 16x extract-min, fp64 exp/laplacian, fp32 out.
// ---------------------------------------------------------------------------
__global__ __launch_bounds__(256) void merge_kernel(
    const float* __restrict__ coords,
    const float* __restrict__ pot,
    const double* __restrict__ sq64,
    const float* __restrict__ s1, const float* __restrict__ sx,
    const unsigned* __restrict__ ctrE,
    const unsigned short* __restrict__ wsknn,
    float* __restrict__ out)
{
    __shared__ double sInv;
    const int tid  = threadIdx.x;
    const int lane = tid & 63;
    const int wave = tid >> 6;
    const int row  = (int)blockIdx.x * 4 + wave;

    if (tid == 0) {
        double S1 = (double)s1[0], m2 = 0.0;
        for (int d = 0; d < DIM; ++d) { double t = (double)sx[d]; m2 += t * t; }
        const double NN = (double)N_PTS;
        sInv = 1.0 / ((2.0 * NN * S1 - 2.0 * m2) / (NN * NN)
                      + 1e-5 + 1e6 / NN + 1e-5);
    }

    const int L = min((int)ctrE[row], CAPR);
    const float4* xip = (const float4*)(coords + row * DIM);
    float4 xi[16];
    #pragma unroll
    for (int q = 0; q < 16; ++q) xi[q] = xip[q];
    const double sqi = sq64[row];

    double dreg[4]; int jreg[4];
    #pragma unroll 1
    for (int b = 0; b < 4; ++b) {
        const int t = b * 64 + lane;
        const int j = (t < L) ? (int)wsknn[row * CAPR + t] : row;
        const float4* xjp = (const float4*)(coords + j * DIM);
        double dot = 0.0;
        #pragma unroll
        for (int q = 0; q < 16; ++q) {
            const float4 a = xi[q], bb = xjp[q];
            dot += (double)a.x * (double)bb.x + (double)a.y * (double)bb.y
                 + (double)a.z * (double)bb.z + (double)a.w * (double)bb.w;
        }
        double d2 = sqi + sq64[j] + 1e-5 - 2.0 * dot;
        if (j == row || t >= L) d2 = 1e300;
        dreg[b] = d2; jreg[b] = j;
    }
    __syncthreads();
    const double inv = sInv;
    const double vr  = (double)pot[row];

    double lap = 0.0;
    #pragma unroll 1
    for (int k = 0; k < KSEL; ++k) {
        double m = dreg[0]; int slot = lane; int jm = jreg[0];
        #pragma unroll
        for (int b = 1; b < 4; ++b)
            if (dreg[b] < m) { m = dreg[b]; slot = b * 64 + lane; jm = jreg[b]; }
        #pragma unroll
        for (int off = 1; off < 64; off <<= 1) {
            const double od = __shfl_xor(m, off, 64);
            const int    os = __shfl_xor(slot, off, 64);
            const int    oj = __shfl_xor(jm, off, 64);
            if (od < m || (od == m && os < slot)) { m = od; slot = os; jm = oj; }
        }
        const double w = exp(-m * inv);
        lap += w * ((double)pot[jm] - vr);
        if ((slot & 63) == lane) {
            const int b2 = slot >> 6;
            #pragma unroll
            for (int b = 0; b < 4; ++b) if (b == b2) dreg[b] = 1e300;
        }
    }
    if (lane == 0) out[row] = (float)lap;
}

extern "C" void kernel_launch(void* const* d_in, const int* in_sizes, int n_in,
                              void* d_out, int out_size, void* d_ws, size_t ws_size,
                              hipStream_t stream)
{
    (void)in_sizes; (void)n_in; (void)out_size; (void)ws_size;
    const float* coords = (const float*)d_in[0];
    const float* pot    = (const float*)d_in[1];
    // d_in[2] is k (always 16, compiled in as KSEL)

    char* w = (char*)d_ws;
    float*    s1   = (float*)w;                        // @0
    float*    s2   = (float*)(w + 4);                  // @4
    float*    sx   = (float*)(w + 16);                 // @16   [64]
    unsigned* ctrT = (unsigned*)(w + 512);             // @512     [4N]
    unsigned* ctrE = (unsigned*)(w + 197120);          // @197120  [N]
    unsigned* flagA= (unsigned*)(w + 246272);          // @246272  [N]
    float*    sq   = (float*)(w + 295424);             // [N]
    double*   sq64 = (double*)(w + 344576);            // [N]
    float*    ts   = (float*)(w + 442880);             // [4N]
    float*    tE   = (float*)(w + 639488);             // [N]
    __bf16*   chi  = (__bf16*)(w + 688640);            // [N*64]
    __bf16*   ea8  = (__bf16*)(w + 2261504);           // [N*8]
    __bf16*   eb8  = (__bf16*)(w + 2458112);           // [N*8]
    unsigned short* wsknn = (unsigned short*)(w + 2654720);  // [N*256]
    // total = 8,946,176 B  (round-5 proved ws_size >= 9,044,480)

    hipMemsetAsync(w, 0, 295424, stream);   // s1,s2,sx,ctrT,ctrE,flagA
    stats_kernel<<<dim3(256), dim3(256), 0, stream>>>(
        coords, s1, s2, sx, sq, sq64, chi, ea8, eb8);
    tcalc_kernel<<<dim3(N_PTS / 256), dim3(256), 0, stream>>>(sq, s1, s2, ts);
    count_kernel<<<dim3(N_PTS / 64, 8), dim3(256), 0, stream>>>(
        chi, ea8, eb8, ts, ctrT);
    tsel_kernel<<<dim3(N_PTS / 256), dim3(256), 0, stream>>>(
        sq, s1, s2, ctrT, flagA, tE);
    emit_kernel<<<dim3(N_PTS / 64, 8), dim3(256), 0, stream>>>(
        chi, ea8, eb8, tE, ctrE, wsknn);
    fallback_kernel<<<dim3(N_PTS / 64), dim3(256), 0, stream>>>(
        coords, sq, flagA, ctrE, wsknn);
    merge_kernel<<<dim3(N_PTS / 4), dim3(256), 0, stream>>>(
        coords, pot, sq64, s1, sx, ctrE, wsknn, (float*)d_out);
}